// Round 8
// baseline (339.135 us; speedup 1.0000x reference)
//
#include <hip/hip_runtime.h>

#define NB 4
#define CC 64
#define HW 4096
#define NT (NB*HW)
#define EPSV 1e-5f
#define LOG2E 1.4426950408889634f

typedef _Float16 f16;
typedef _Float16 half4 __attribute__((ext_vector_type(4)));
typedef _Float16 half8 __attribute__((ext_vector_type(8)));
typedef float   float4v __attribute__((ext_vector_type(4)));

#define NELEM ((size_t)NB*HW*CC)   // 1,048,576 per tensor

// ws: fp32 [256..511] folded scale/shift (sq,tq,sk,tk — K pair pre-scaled by
// log2e). [512..512+65536): per-(n,bx) partial BN stats (256 slots x 256).
// Byte 264192+: f16 q, k ([n][hw][c]) and gv ([n][c][hw]) — 3 x 2 MB.
#define PART_OFF 512
#define TEN_OFF  264192

// ---------------------------------------------------------------------------
// conv2: 3 fused 1x1 convs. Output channels split across blockIdx.z (2 halves)
// so the LDS W-tile is 24 KB -> 2 blocks/CU, 16 waves/CU. No atomics: partial
// BN stats to private slots (disjoint channel ranges per z).
// grid (HW/64, NB, 2), 512 thr. Thread: px = t&63, grp = t>>6 -> 4 channels.
// ---------------------------------------------------------------------------
__global__ __launch_bounds__(512)
void conv2_kernel(const float* __restrict__ x,
                  const float* __restrict__ h0, const float* __restrict__ h1,
                  const float* __restrict__ Wq, const float* __restrict__ bq,
                  const float* __restrict__ Wk, const float* __restrict__ bk,
                  const float* __restrict__ Wv, const float* __restrict__ bv,
                  float* __restrict__ ws,
                  f16* __restrict__ q, f16* __restrict__ k, f16* __restrict__ gv)
{
    __shared__ float Wl[3][32*CC];   // 24 KB (this z-half's 32 rows x 3 convs)
    __shared__ float xs[CC][64];     // 16 KB
    const int t   = threadIdx.x;
    const int n   = blockIdx.y;
    const int z   = blockIdx.z;
    const int px0 = blockIdx.x * 64;
    const int px  = t & 63;
    const int grp = t >> 6;          // wave index (wave-uniform)
    const int ocl = grp * 4;         // local W row base
    const int oc0 = z*32 + ocl;      // absolute out-channel base

    // W stage: rows [z*32, z*32+32) are contiguous — one float4 per thread/conv
    ((float4*)Wl[0])[t] = ((const float4*)(Wq + (size_t)z*32*CC))[t];
    ((float4*)Wl[1])[t] = ((const float4*)(Wk + (size_t)z*32*CC))[t];
    ((float4*)Wl[2])[t] = ((const float4*)(Wv + (size_t)z*32*CC))[t];
    for (int i = t; i < CC*64; i += 512) {
        int ic = i >> 6, p = i & 63;
        xs[ic][p] = x[((size_t)n*CC + ic)*HW + px0 + p];
    }
    __syncthreads();

    float aq[4], ak[4], av[4];
    #pragma unroll
    for (int j = 0; j < 4; ++j) { aq[j] = bq[oc0+j]; ak[j] = bk[oc0+j]; av[j] = bv[oc0+j]; }

    for (int ic = 0; ic < CC; ic += 4) {
        float xv0 = xs[ic  ][px];
        float xv1 = xs[ic+1][px];
        float xv2 = xs[ic+2][px];
        float xv3 = xs[ic+3][px];
        #pragma unroll
        for (int j = 0; j < 4; ++j) {
            const int row = (ocl+j)*CC + ic;
            float4 wq = *(const float4*)&Wl[0][row];
            float4 wk = *(const float4*)&Wl[1][row];
            float4 wv = *(const float4*)&Wl[2][row];
            aq[j] = fmaf(wq.x,xv0, fmaf(wq.y,xv1, fmaf(wq.z,xv2, fmaf(wq.w,xv3, aq[j]))));
            ak[j] = fmaf(wk.x,xv0, fmaf(wk.y,xv1, fmaf(wk.z,xv2, fmaf(wk.w,xv3, ak[j]))));
            av[j] = fmaf(wv.x,xv0, fmaf(wv.y,xv1, fmaf(wv.z,xv2, fmaf(wv.w,xv3, av[j]))));
        }
    }

    // raw q,k stores (f16, [hw][c] layout)
    const size_t base = ((size_t)n*HW + px0 + px)*CC + oc0;
    half4 vq, vk;
    #pragma unroll
    for (int j = 0; j < 4; ++j) { vq[j] = (f16)aq[j]; vk[j] = (f16)ak[j]; }
    *(half4*)&q[base] = vq;
    *(half4*)&k[base] = vk;

    // gated V ([c][hw] layout)
    #pragma unroll
    for (int j = 0; j < 4; ++j) {
        size_t gi = ((size_t)n*CC + oc0 + j)*HW + px0 + px;
        gv[gi] = (f16)((h0[gi] + h1[gi]) * av[j]);
    }

    // BN partial stats: full-wave reduce per channel, lane-0 private stores
    float* slot = ws + PART_OFF + (size_t)(n*(HW/64) + blockIdx.x)*256;
    #pragma unroll
    for (int j = 0; j < 4; ++j) {
        float v0 = aq[j], v1 = aq[j]*aq[j], v2 = ak[j], v3 = ak[j]*ak[j];
        #pragma unroll
        for (int off = 32; off > 0; off >>= 1) {
            v0 += __shfl_down(v0, off);
            v1 += __shfl_down(v1, off);
            v2 += __shfl_down(v2, off);
            v3 += __shfl_down(v3, off);
        }
        if (px == 0) {
            slot[      oc0 + j] = v0;
            slot[ 64 + oc0 + j] = v1;
            slot[128 + oc0 + j] = v2;
            slot[192 + oc0 + j] = v3;
        }
    }
}

// ---------------------------------------------------------------------------
// bnstats: tree-sum the 256 per-slot partials, fold BN into scale/shift.
// K pair pre-multiplied by log2e (softmax uses exp2). 1 block x 256 thr.
// ---------------------------------------------------------------------------
__global__ __launch_bounds__(256)
void bnstats_kernel(const float* __restrict__ gq, const float* __restrict__ betaq,
                    const float* __restrict__ gk, const float* __restrict__ betak,
                    float* __restrict__ ws)
{
    __shared__ float tot[256];
    const int i = threadIdx.x;
    float acc = 0.0f;
    #pragma unroll 8
    for (int b = 0; b < 256; ++b) acc += ws[PART_OFF + b*256 + i];
    tot[i] = acc;
    __syncthreads();

    if (i < 64) {
        float mean = tot[i] * (1.0f / NT);
        float var  = tot[64 + i] * (1.0f / NT) - mean*mean;
        float s    = gq[i] * rsqrtf(var + EPSV);
        ws[256 + i] = s;
        ws[320 + i] = betaq[i] - mean*s;
    } else if (i < 128) {
        int c = i - 64;
        float mean = tot[128 + c] * (1.0f / NT);
        float var  = tot[192 + c] * (1.0f / NT) - mean*mean;
        float s    = gk[c] * rsqrtf(var + EPSV);
        ws[384 + c] = s * LOG2E;
        ws[448 + c] = (betak[c] - mean*s) * LOG2E;
    }
}

// ---------------------------------------------------------------------------
// apply: in-place y = relu(s*y + t) on the f16 tensors. blockIdx.y: 0=q, 1=k.
// ---------------------------------------------------------------------------
__global__ __launch_bounds__(256)
void apply_kernel(f16* __restrict__ q, f16* __restrict__ k,
                  const float* __restrict__ ws)
{
    __shared__ float sc[CC], sh[CC];
    const int t = threadIdx.x;
    const int tens = blockIdx.y;
    if (t < 64)       sc[t]    = ws[256 + tens*128 + t];
    else if (t < 128) sh[t-64] = ws[320 + tens*128 + (t-64)];
    __syncthreads();

    f16* p = tens ? k : q;
    const size_t e0 = ((size_t)blockIdx.x * 256 + t) * 8;
    const int c0 = (int)(e0 & 63);

    half8 v = *(half8*)&p[e0];
    half8 o;
    #pragma unroll
    for (int j = 0; j < 8; ++j)
        o[j] = (f16)fmaxf(fmaf(sc[c0+j], (float)v[j], sh[c0+j]), 0.0f);
    *(half8*)&p[e0] = o;
}

// ---------------------------------------------------------------------------
// MFMA flash attention, S^T form, two-pass, 16 q-rows/block.
// grid (HW/16, NB) = 1024 blocks -> 4 blocks/CU, 16 waves/CU, 4 waves/SIMD.
// Wave w owns K-quarter [w*1024, +1024); plain-sum merge (shared M).
// Layout (validated r4-r7): mfma(X,Y) -> D[p=quad*4+reg <- X row][q=lane&15 <- Y row].
// ---------------------------------------------------------------------------
__global__ __launch_bounds__(256, 4)
void attn_kernel(const f16* __restrict__ q, const f16* __restrict__ k,
                 const f16* __restrict__ gv, float* __restrict__ out)
{
    __shared__ float Obuf[3][CC][16];         // waves 1..3 partial O^T (12 KB)
    __shared__ float Mbuf[4][16];
    __shared__ float Lbuf[3][16];

    const int t    = threadIdx.x;
    const int n    = blockIdx.y;
    const int w    = t >> 6;
    const int lane = t & 63;
    const int m16  = lane & 15;
    const int kb   = lane >> 4;
    const int q0   = blockIdx.x * 16;

    // Q fragment (Y-operand): Y[q=qrow=lane&15][k=ch=chalf*32+kb*8+j]
    const size_t qb = ((size_t)n*HW + q0 + m16)*CC + kb*8;
    const half8 qf0 = *(const half8*)&q[qb];
    const half8 qf1 = *(const half8*)&q[qb + 32];

    const int    kt0   = w * (HW/4);
    const size_t krow  = (size_t)n*HW*CC;
    const size_t gbase = ((size_t)n*CC + m16)*HW;

    half8 khf[2][2][2];     // [buf][ktile][chalf]
    half4 gvf[2][2][4];     // [buf][ktile][ct]

#define LOADK(B, KT) do {                                                     \
    size_t a_ = krow + ((size_t)(KT) + m16)*CC + kb*8;                        \
    khf[B][0][0] = *(const half8*)&k[a_];                                     \
    khf[B][0][1] = *(const half8*)&k[a_ + 32];                                \
    khf[B][1][0] = *(const half8*)&k[a_ + 16*CC];                             \
    khf[B][1][1] = *(const half8*)&k[a_ + 16*CC + 32];                        \
} while (0)

#define LOADGV(B, KT) do {                                                    \
    size_t g_ = gbase + (size_t)(KT) + kb*4;                                  \
    _Pragma("unroll") for (int k2_ = 0; k2_ < 2; ++k2_)                       \
    _Pragma("unroll") for (int ct_ = 0; ct_ < 4; ++ct_)                       \
        gvf[B][k2_][ct_] = *(const half4*)&gv[g_ + k2_*16 + (size_t)ct_*16*HW];\
} while (0)

#define SMFMA(B, accS) do {                                                   \
    _Pragma("unroll") for (int k2_ = 0; k2_ < 2; ++k2_) {                     \
        float4v z_ = {0.f,0.f,0.f,0.f};                                       \
        z_ = __builtin_amdgcn_mfma_f32_16x16x32_f16(khf[B][k2_][0], qf0, z_, 0,0,0); \
        accS[k2_] = __builtin_amdgcn_mfma_f32_16x16x32_f16(khf[B][k2_][1], qf1, z_, 0,0,0); \
    }                                                                         \
} while (0)

    // ---------------- pass 1: exact global row max (no cross-lane in loop)
    float mloc = -INFINITY;

#define STEP1(B, NB_, KTN) do {                                               \
    LOADK(NB_, KTN);                                                          \
    float4v accS[2];                                                          \
    SMFMA(B, accS);                                                           \
    float a_ = fmaxf(fmaxf(fmaxf(accS[0][0], accS[0][1]),                     \
                           fmaxf(accS[0][2], accS[0][3])),                    \
                     fmaxf(fmaxf(accS[1][0], accS[1][1]),                     \
                           fmaxf(accS[1][2], accS[1][3])));                   \
    mloc = fmaxf(mloc, a_);                                                   \
} while (0)

    LOADK(0, kt0);
    for (int i2 = 0; i2 < 16; ++i2) {
        const int kA = kt0 + i2*64;
        STEP1(0, 1, kA + 32);
        STEP1(1, 0, kA + 64);   // final prefetch overreads into gv region: unused, in-bounds of ws
    }

    mloc = fmaxf(mloc, __shfl_xor(mloc, 16));
    mloc = fmaxf(mloc, __shfl_xor(mloc, 32));
    if (kb == 0) Mbuf[w][m16] = mloc;
    __syncthreads();

    const float M = fmaxf(fmaxf(Mbuf[0][m16], Mbuf[1][m16]),
                          fmaxf(Mbuf[2][m16], Mbuf[3][m16]));

    // ---------------- pass 2: rescale-free accumulate
    float4v accO[4];
    #pragma unroll
    for (int ct = 0; ct < 4; ++ct) accO[ct] = (float4v){0.f,0.f,0.f,0.f};
    float l = 0.0f;

#define STEP2(B, NB_, KTN) do {                                               \
    LOADK(NB_, KTN);                                                          \
    LOADGV(NB_, KTN);                                                         \
    float4v accS[2];                                                          \
    SMFMA(B, accS);                                                           \
    float p0 = exp2f(accS[0][0] - M), p1 = exp2f(accS[0][1] - M);             \
    float p2 = exp2f(accS[0][2] - M), p3 = exp2f(accS[0][3] - M);             \
    float p4 = exp2f(accS[1][0] - M), p5 = exp2f(accS[1][1] - M);             \
    float p6 = exp2f(accS[1][2] - M), p7 = exp2f(accS[1][3] - M);             \
    l += ((p0+p1)+(p2+p3)) + ((p4+p5)+(p6+p7));                               \
    half4 pfa, pfb;                                                           \
    pfa[0]=(f16)p0; pfa[1]=(f16)p1; pfa[2]=(f16)p2; pfa[3]=(f16)p3;           \
    pfb[0]=(f16)p4; pfb[1]=(f16)p5; pfb[2]=(f16)p6; pfb[3]=(f16)p7;           \
    _Pragma("unroll") for (int ct_ = 0; ct_ < 4; ++ct_) {                     \
        float4v o_ = accO[ct_];                                               \
        o_ = __builtin_amdgcn_mfma_f32_16x16x16f16(gvf[B][0][ct_], pfa, o_, 0,0,0); \
        accO[ct_] = __builtin_amdgcn_mfma_f32_16x16x16f16(gvf[B][1][ct_], pfb, o_, 0,0,0); \
    }                                                                         \
} while (0)

    LOADK(0, kt0);
    LOADGV(0, kt0);
    for (int i2 = 0; i2 < 16; ++i2) {
        const int kA = kt0 + i2*64;
        STEP2(0, 1, kA + 32);
        STEP2(1, 0, kA + 64);   // final prefetch overread: unused, in-bounds of ws
    }

    // l per q-row: reduce across the 4 quads (once)
    l += __shfl_xor(l, 16);
    l += __shfl_xor(l, 32);

    if (w > 0) {
        #pragma unroll
        for (int ct = 0; ct < 4; ++ct)
            #pragma unroll
            for (int r = 0; r < 4; ++r)
                Obuf[w-1][ct*16 + kb*4 + r][m16] = accO[ct][r];
        if (kb == 0) Lbuf[w-1][m16] = l;
    }
    __syncthreads();

    if (w == 0) {
        float lt  = l + Lbuf[0][m16] + Lbuf[1][m16] + Lbuf[2][m16];
        float inv = 1.0f / lt;
        #pragma unroll
        for (int ct = 0; ct < 4; ++ct) {
            #pragma unroll
            for (int r = 0; r < 4; ++r) {
                int ch = ct*16 + kb*4 + r;
                float o = accO[ct][r]
                        + Obuf[0][ch][m16] + Obuf[1][ch][m16] + Obuf[2][ch][m16];
                out[((size_t)n*CC + ch)*HW + q0 + m16] = o * inv;
            }
        }
    }
#undef STEP2
#undef STEP1
#undef SMFMA
#undef LOADGV
#undef LOADK
}

// ---------------------------------------------------------------------------
extern "C" void kernel_launch(void* const* d_in, const int* in_sizes, int n_in,
                              void* d_out, int out_size, void* d_ws, size_t ws_size,
                              hipStream_t stream)
{
    const float* low   = (const float*)d_in[0];
    const float* h0    = (const float*)d_in[1];
    const float* h1    = (const float*)d_in[2];
    const float* Wq    = (const float*)d_in[3];
    const float* bq    = (const float*)d_in[4];
    const float* gq    = (const float*)d_in[5];
    const float* betaq = (const float*)d_in[6];
    const float* Wk    = (const float*)d_in[7];
    const float* bk    = (const float*)d_in[8];
    const float* gk    = (const float*)d_in[9];
    const float* betak = (const float*)d_in[10];
    const float* Wv    = (const float*)d_in[11];
    const float* bv    = (const float*)d_in[12];

    float* wsf = (float*)d_ws;
    float* out = (float*)d_out;

    f16* q  = (f16*)((char*)d_ws + TEN_OFF);
    f16* k  = q + NELEM;
    f16* gv = k + NELEM;

    conv2_kernel<<<dim3(HW/64, NB, 2), 512, 0, stream>>>(
        low, h0, h1, Wq, bq, Wk, bk, Wv, bv, wsf, q, k, gv);

    bnstats_kernel<<<1, 256, 0, stream>>>(gq, betaq, gk, betak, wsf);

    apply_kernel<<<dim3((int)(NELEM/(256*8)), 2), 256, 0, stream>>>(q, k, wsf);

    attn_kernel<<<dim3(HW/16, NB), 256, 0, stream>>>(q, k, gv, out);
}

// Round 9
// 182.228 us; speedup vs baseline: 1.8611x; 1.8611x over previous
//
#include <hip/hip_runtime.h>

#define NB 4
#define CC 64
#define HW 4096
#define NT (NB*HW)
#define EPSV 1e-5f
#define LOG2E 1.4426950408889634f

typedef _Float16 f16;
typedef _Float16 half4 __attribute__((ext_vector_type(4)));
typedef _Float16 half8 __attribute__((ext_vector_type(8)));
typedef float   float4v __attribute__((ext_vector_type(4)));

#define NELEM ((size_t)NB*HW*CC)   // 1,048,576 per tensor

// ws: fp32 [256..511] folded scale/shift (sq,tq,sk,tk — K pair pre-scaled by
// log2e). [512..512+65536): per-(n,bx) partial BN stats (256 slots x 256).
// Byte 264192+: f16 q, k ([n][hw][c]) and gv ([n][c][hw]) — 3 x 2 MB.
#define PART_OFF 512
#define TEN_OFF  264192

// ---------------------------------------------------------------------------
// conv2: 3 fused 1x1 convs, channel-split over blockIdx.z (unchanged from r8).
// ---------------------------------------------------------------------------
__global__ __launch_bounds__(512)
void conv2_kernel(const float* __restrict__ x,
                  const float* __restrict__ h0, const float* __restrict__ h1,
                  const float* __restrict__ Wq, const float* __restrict__ bq,
                  const float* __restrict__ Wk, const float* __restrict__ bk,
                  const float* __restrict__ Wv, const float* __restrict__ bv,
                  float* __restrict__ ws,
                  f16* __restrict__ q, f16* __restrict__ k, f16* __restrict__ gv)
{
    __shared__ float Wl[3][32*CC];   // 24 KB
    __shared__ float xs[CC][64];     // 16 KB
    const int t   = threadIdx.x;
    const int n   = blockIdx.y;
    const int z   = blockIdx.z;
    const int px0 = blockIdx.x * 64;
    const int px  = t & 63;
    const int grp = t >> 6;
    const int ocl = grp * 4;
    const int oc0 = z*32 + ocl;

    ((float4*)Wl[0])[t] = ((const float4*)(Wq + (size_t)z*32*CC))[t];
    ((float4*)Wl[1])[t] = ((const float4*)(Wk + (size_t)z*32*CC))[t];
    ((float4*)Wl[2])[t] = ((const float4*)(Wv + (size_t)z*32*CC))[t];
    for (int i = t; i < CC*64; i += 512) {
        int ic = i >> 6, p = i & 63;
        xs[ic][p] = x[((size_t)n*CC + ic)*HW + px0 + p];
    }
    __syncthreads();

    float aq[4], ak[4], av[4];
    #pragma unroll
    for (int j = 0; j < 4; ++j) { aq[j] = bq[oc0+j]; ak[j] = bk[oc0+j]; av[j] = bv[oc0+j]; }

    for (int ic = 0; ic < CC; ic += 4) {
        float xv0 = xs[ic  ][px];
        float xv1 = xs[ic+1][px];
        float xv2 = xs[ic+2][px];
        float xv3 = xs[ic+3][px];
        #pragma unroll
        for (int j = 0; j < 4; ++j) {
            const int row = (ocl+j)*CC + ic;
            float4 wq = *(const float4*)&Wl[0][row];
            float4 wk = *(const float4*)&Wl[1][row];
            float4 wv = *(const float4*)&Wl[2][row];
            aq[j] = fmaf(wq.x,xv0, fmaf(wq.y,xv1, fmaf(wq.z,xv2, fmaf(wq.w,xv3, aq[j]))));
            ak[j] = fmaf(wk.x,xv0, fmaf(wk.y,xv1, fmaf(wk.z,xv2, fmaf(wk.w,xv3, ak[j]))));
            av[j] = fmaf(wv.x,xv0, fmaf(wv.y,xv1, fmaf(wv.z,xv2, fmaf(wv.w,xv3, av[j]))));
        }
    }

    const size_t base = ((size_t)n*HW + px0 + px)*CC + oc0;
    half4 vq, vk;
    #pragma unroll
    for (int j = 0; j < 4; ++j) { vq[j] = (f16)aq[j]; vk[j] = (f16)ak[j]; }
    *(half4*)&q[base] = vq;
    *(half4*)&k[base] = vk;

    #pragma unroll
    for (int j = 0; j < 4; ++j) {
        size_t gi = ((size_t)n*CC + oc0 + j)*HW + px0 + px;
        gv[gi] = (f16)((h0[gi] + h1[gi]) * av[j]);
    }

    float* slot = ws + PART_OFF + (size_t)(n*(HW/64) + blockIdx.x)*256;
    #pragma unroll
    for (int j = 0; j < 4; ++j) {
        float v0 = aq[j], v1 = aq[j]*aq[j], v2 = ak[j], v3 = ak[j]*ak[j];
        #pragma unroll
        for (int off = 32; off > 0; off >>= 1) {
            v0 += __shfl_down(v0, off);
            v1 += __shfl_down(v1, off);
            v2 += __shfl_down(v2, off);
            v3 += __shfl_down(v3, off);
        }
        if (px == 0) {
            slot[      oc0 + j] = v0;
            slot[ 64 + oc0 + j] = v1;
            slot[128 + oc0 + j] = v2;
            slot[192 + oc0 + j] = v3;
        }
    }
}

// ---------------------------------------------------------------------------
__global__ __launch_bounds__(256)
void bnstats_kernel(const float* __restrict__ gq, const float* __restrict__ betaq,
                    const float* __restrict__ gk, const float* __restrict__ betak,
                    float* __restrict__ ws)
{
    __shared__ float tot[256];
    const int i = threadIdx.x;
    float acc = 0.0f;
    #pragma unroll 8
    for (int b = 0; b < 256; ++b) acc += ws[PART_OFF + b*256 + i];
    tot[i] = acc;
    __syncthreads();

    if (i < 64) {
        float mean = tot[i] * (1.0f / NT);
        float var  = tot[64 + i] * (1.0f / NT) - mean*mean;
        float s    = gq[i] * rsqrtf(var + EPSV);
        ws[256 + i] = s;
        ws[320 + i] = betaq[i] - mean*s;
    } else if (i < 128) {
        int c = i - 64;
        float mean = tot[128 + c] * (1.0f / NT);
        float var  = tot[192 + c] * (1.0f / NT) - mean*mean;
        float s    = gk[c] * rsqrtf(var + EPSV);
        ws[384 + c] = s * LOG2E;
        ws[448 + c] = (betak[c] - mean*s) * LOG2E;
    }
}

// ---------------------------------------------------------------------------
__global__ __launch_bounds__(256)
void apply_kernel(f16* __restrict__ q, f16* __restrict__ k,
                  const float* __restrict__ ws)
{
    __shared__ float sc[CC], sh[CC];
    const int t = threadIdx.x;
    const int tens = blockIdx.y;
    if (t < 64)       sc[t]    = ws[256 + tens*128 + t];
    else if (t < 128) sh[t-64] = ws[320 + tens*128 + (t-64)];
    __syncthreads();

    f16* p = tens ? k : q;
    const size_t e0 = ((size_t)blockIdx.x * 256 + t) * 8;
    const int c0 = (int)(e0 & 63);

    half8 v = *(half8*)&p[e0];
    half8 o;
    #pragma unroll
    for (int j = 0; j < 8; ++j)
        o[j] = (f16)fmaxf(fmaf(sc[c0+j], (float)v[j], sh[c0+j]), 0.0f);
    *(half8*)&p[e0] = o;
}

// ---------------------------------------------------------------------------
// MFMA flash attention, S^T form, ONLINE single-pass, 64 q-rows/block.
// grid (HW/64, NB) = 256 blocks, 512 thr (8 waves). Wave w owns keys
// [w*512, +512); each wave covers all 4 q-tiles -> K+GV read ONCE per block
// (1 MB/block, 256 MB total vs r8's 1.5 GB — the L2-BW bound at ~6.3 TB/s
// was the r7/r8 limiter). 8-way merge: m/l via LDS, O via 4 staged rounds.
// Layout (validated r4-r8): mfma(X,Y) -> D[p=quad*4+reg <- X row][q=lane&15 <- Y row].
// ---------------------------------------------------------------------------
__global__ __launch_bounds__(512, 2)
void attn_kernel(const f16* __restrict__ q, const f16* __restrict__ k,
                 const f16* __restrict__ gv, float* __restrict__ out)
{
    __shared__ float Obuf[8][4][256];   // [wave][ct][lane*4] — 32 KB, reused 4x
    __shared__ float MLbuf[2][8][64];   // [m|l][wave][qrow]  — 4 KB

    const int t    = threadIdx.x;
    const int n    = blockIdx.y;
    const int w    = t >> 6;
    const int lane = t & 63;
    const int m16  = lane & 15;
    const int kb   = lane >> 4;
    const int q0   = blockIdx.x * 64;

    // Q fragments (Y-operand) for 4 q-tiles
    half8 qf[4][2];
    #pragma unroll
    for (int qt = 0; qt < 4; ++qt) {
        const size_t qb = ((size_t)n*HW + q0 + qt*16 + m16)*CC + kb*8;
        qf[qt][0] = *(const half8*)&q[qb];
        qf[qt][1] = *(const half8*)&q[qb + 32];
    }

    const int    kt0   = w * 512;
    const size_t krow  = (size_t)n*HW*CC;
    const size_t gbase = ((size_t)n*CC + m16)*HW;

    half8 khf[2][2][2];     // [buf][ktile][chalf]
    half4 gvf[2][2][4];     // [buf][ktile][ct]

#define LOADK(B, KT) do {                                                     \
    size_t a_ = krow + ((size_t)(KT) + m16)*CC + kb*8;                        \
    khf[B][0][0] = *(const half8*)&k[a_];                                     \
    khf[B][0][1] = *(const half8*)&k[a_ + 32];                                \
    khf[B][1][0] = *(const half8*)&k[a_ + 16*CC];                             \
    khf[B][1][1] = *(const half8*)&k[a_ + 16*CC + 32];                        \
} while (0)

#define LOADGV(B, KT) do {                                                    \
    size_t g_ = gbase + (size_t)(KT) + kb*4;                                  \
    _Pragma("unroll") for (int k2_ = 0; k2_ < 2; ++k2_)                       \
    _Pragma("unroll") for (int ct_ = 0; ct_ < 4; ++ct_)                       \
        gvf[B][k2_][ct_] = *(const half4*)&gv[g_ + k2_*16 + (size_t)ct_*16*HW];\
} while (0)

    float4v accO[4][4];
    #pragma unroll
    for (int qt = 0; qt < 4; ++qt)
        #pragma unroll
        for (int ct = 0; ct < 4; ++ct) accO[qt][ct] = (float4v){0.f,0.f,0.f,0.f};
    float m[4] = {-INFINITY,-INFINITY,-INFINITY,-INFINITY};
    float l[4] = {0.f,0.f,0.f,0.f};

#define STEP(B, NB_, KTN) do {                                                \
    LOADK(NB_, KTN);                                                          \
    LOADGV(NB_, KTN);                                                         \
    float4v accS[4][2];                                                       \
    _Pragma("unroll") for (int qt_ = 0; qt_ < 4; ++qt_)                       \
    _Pragma("unroll") for (int k2_ = 0; k2_ < 2; ++k2_) {                     \
        float4v z_ = {0.f,0.f,0.f,0.f};                                       \
        z_ = __builtin_amdgcn_mfma_f32_16x16x32_f16(khf[B][k2_][0], qf[qt_][0], z_, 0,0,0); \
        accS[qt_][k2_] = __builtin_amdgcn_mfma_f32_16x16x32_f16(khf[B][k2_][1], qf[qt_][1], z_, 0,0,0); \
    }                                                                         \
    _Pragma("unroll") for (int qt_ = 0; qt_ < 4; ++qt_) {                     \
        float mx = fmaxf(fmaxf(fmaxf(accS[qt_][0][0], accS[qt_][0][1]),       \
                               fmaxf(accS[qt_][0][2], accS[qt_][0][3])),      \
                         fmaxf(fmaxf(accS[qt_][1][0], accS[qt_][1][1]),       \
                               fmaxf(accS[qt_][1][2], accS[qt_][1][3])));     \
        mx = fmaxf(mx, __shfl_xor(mx, 16));                                   \
        mx = fmaxf(mx, __shfl_xor(mx, 32));                                   \
        float mn = fmaxf(m[qt_], mx);                                         \
        float al = exp2f(m[qt_] - mn);  m[qt_] = mn;                          \
        float p0 = exp2f(accS[qt_][0][0]-mn), p1 = exp2f(accS[qt_][0][1]-mn); \
        float p2 = exp2f(accS[qt_][0][2]-mn), p3 = exp2f(accS[qt_][0][3]-mn); \
        float p4 = exp2f(accS[qt_][1][0]-mn), p5 = exp2f(accS[qt_][1][1]-mn); \
        float p6 = exp2f(accS[qt_][1][2]-mn), p7 = exp2f(accS[qt_][1][3]-mn); \
        l[qt_] = fmaf(l[qt_], al, ((p0+p1)+(p2+p3)) + ((p4+p5)+(p6+p7)));     \
        half4 pfa, pfb;                                                       \
        pfa[0]=(f16)p0; pfa[1]=(f16)p1; pfa[2]=(f16)p2; pfa[3]=(f16)p3;       \
        pfb[0]=(f16)p4; pfb[1]=(f16)p5; pfb[2]=(f16)p6; pfb[3]=(f16)p7;       \
        _Pragma("unroll") for (int ct_ = 0; ct_ < 4; ++ct_) {                 \
            float4v o_ = accO[qt_][ct_];                                      \
            o_[0]*=al; o_[1]*=al; o_[2]*=al; o_[3]*=al;                       \
            o_ = __builtin_amdgcn_mfma_f32_16x16x16f16(gvf[B][0][ct_], pfa, o_, 0,0,0); \
            accO[qt_][ct_] = __builtin_amdgcn_mfma_f32_16x16x16f16(gvf[B][1][ct_], pfb, o_, 0,0,0); \
        }                                                                     \
    }                                                                         \
} while (0)

    LOADK(0, kt0);
    LOADGV(0, kt0);
    for (int i2 = 0; i2 < 8; ++i2) {
        const int kA = kt0 + i2*64;
        STEP(0, 1, kA + 32);
        STEP(1, 0, kA + 64);   // final prefetch overreads into ws slack: unused
    }

    // per-qt l: reduce across the 4 quads; publish (m,l) per q-row
    #pragma unroll
    for (int qt = 0; qt < 4; ++qt) {
        l[qt] += __shfl_xor(l[qt], 16);
        l[qt] += __shfl_xor(l[qt], 32);
    }
    if (kb == 0) {
        #pragma unroll
        for (int qt = 0; qt < 4; ++qt) {
            MLbuf[0][w][qt*16 + m16] = m[qt];
            MLbuf[1][w][qt*16 + m16] = l[qt];
        }
    }
    __syncthreads();

    // global M, L per q-row; scale own partials into the shared frame
    float invL[4];
    #pragma unroll
    for (int qt = 0; qt < 4; ++qt) {
        const int r = qt*16 + m16;
        float M = MLbuf[0][0][r];
        #pragma unroll
        for (int src = 1; src < 8; ++src) M = fmaxf(M, MLbuf[0][src][r]);
        float L = 0.0f;
        #pragma unroll
        for (int src = 0; src < 8; ++src)
            L += MLbuf[1][src][r] * exp2f(MLbuf[0][src][r] - M);
        const float f = exp2f(m[qt] - M);
        #pragma unroll
        for (int ct = 0; ct < 4; ++ct) {
            accO[qt][ct][0] *= f; accO[qt][ct][1] *= f;
            accO[qt][ct][2] *= f; accO[qt][ct][3] *= f;
        }
        invL[qt] = 1.0f / L;
    }

    // 4 staged merge rounds: round r handles q-tile r (4 ct pairs)
    for (int rd = 0; rd < 4; ++rd) {
        __syncthreads();   // prior round's reads done before overwrite
        #pragma unroll
        for (int ct = 0; ct < 4; ++ct)
            ((float4*)&Obuf[w][ct][0])[lane] =
                (float4){accO[rd][ct][0], accO[rd][ct][1], accO[rd][ct][2], accO[rd][ct][3]};
        __syncthreads();
        if (w < 4) {   // wave ct=w sums its pair across the 8 sources
            float4 s = ((float4*)&Obuf[0][w][0])[lane];
            #pragma unroll
            for (int src = 1; src < 8; ++src) {
                float4 v = ((float4*)&Obuf[src][w][0])[lane];
                s.x += v.x; s.y += v.y; s.z += v.z; s.w += v.w;
            }
            const float iv = invL[rd];
            const int chb = w*16 + kb*4;
            const int row = q0 + rd*16 + m16;
            out[((size_t)n*CC + chb + 0)*HW + row] = s.x * iv;
            out[((size_t)n*CC + chb + 1)*HW + row] = s.y * iv;
            out[((size_t)n*CC + chb + 2)*HW + row] = s.z * iv;
            out[((size_t)n*CC + chb + 3)*HW + row] = s.w * iv;
        }
    }
#undef STEP
#undef LOADGV
#undef LOADK
}

// ---------------------------------------------------------------------------
extern "C" void kernel_launch(void* const* d_in, const int* in_sizes, int n_in,
                              void* d_out, int out_size, void* d_ws, size_t ws_size,
                              hipStream_t stream)
{
    const float* low   = (const float*)d_in[0];
    const float* h0    = (const float*)d_in[1];
    const float* h1    = (const float*)d_in[2];
    const float* Wq    = (const float*)d_in[3];
    const float* bq    = (const float*)d_in[4];
    const float* gq    = (const float*)d_in[5];
    const float* betaq = (const float*)d_in[6];
    const float* Wk    = (const float*)d_in[7];
    const float* bk    = (const float*)d_in[8];
    const float* gk    = (const float*)d_in[9];
    const float* betak = (const float*)d_in[10];
    const float* Wv    = (const float*)d_in[11];
    const float* bv    = (const float*)d_in[12];

    float* wsf = (float*)d_ws;
    float* out = (float*)d_out;

    f16* q  = (f16*)((char*)d_ws + TEN_OFF);
    f16* k  = q + NELEM;
    f16* gv = k + NELEM;

    conv2_kernel<<<dim3(HW/64, NB, 2), 512, 0, stream>>>(
        low, h0, h1, Wq, bq, Wk, bk, Wv, bv, wsf, q, k, gv);

    bnstats_kernel<<<1, 256, 0, stream>>>(gq, betaq, gk, betak, wsf);

    apply_kernel<<<dim3((int)(NELEM/(256*8)), 2), 256, 0, stream>>>(q, k, wsf);

    attn_kernel<<<dim3(HW/64, NB), 512, 0, stream>>>(q, k, gv, out);
}

// Round 11
// 164.566 us; speedup vs baseline: 2.0608x; 1.1073x over previous
//
#include <hip/hip_runtime.h>

#define NB 4
#define CC 64
#define HW 4096
#define NT (NB*HW)
#define EPSV 1e-5f
#define LOG2E 1.4426950408889634f

typedef _Float16 f16;
typedef _Float16 half4 __attribute__((ext_vector_type(4)));
typedef _Float16 half8 __attribute__((ext_vector_type(8)));
typedef float   float4v __attribute__((ext_vector_type(4)));

#define NELEM ((size_t)NB*HW*CC)   // 1,048,576 per tensor

// ws: fp32 [256..511] folded scale/shift (sq,tq,sk,tk — K pair pre-scaled by
// log2e). [512..512+65536): per-(n,bx) partial BN stats (256 slots x 256).
// Byte 264192+: f16 q, k ([n][hw][c]) and gv ([n][c][hw]) — 3 x 2 MB.
#define PART_OFF 512
#define TEN_OFF  264192

// ---------------------------------------------------------------------------
// conv2: 3 fused 1x1 convs, 4-way channel split over blockIdx.z (r10 version).
// grid (HW/64, NB, 4), 256 thr. 28 KB LDS -> 4-5 blocks/CU.
// ---------------------------------------------------------------------------
__global__ __launch_bounds__(256)
void conv2_kernel(const float* __restrict__ x,
                  const float* __restrict__ h0, const float* __restrict__ h1,
                  const float* __restrict__ Wq, const float* __restrict__ bq,
                  const float* __restrict__ Wk, const float* __restrict__ bk,
                  const float* __restrict__ Wv, const float* __restrict__ bv,
                  float* __restrict__ ws,
                  f16* __restrict__ q, f16* __restrict__ k, f16* __restrict__ gv)
{
    __shared__ float Wl[3][16*CC];   // 12 KB
    __shared__ float xs[CC][64];     // 16 KB
    const int t   = threadIdx.x;
    const int n   = blockIdx.y;
    const int z   = blockIdx.z;
    const int px0 = blockIdx.x * 64;
    const int px  = t & 63;
    const int grp = t >> 6;
    const int ocl = grp * 4;
    const int oc0 = z*16 + ocl;

    ((float4*)Wl[0])[t] = ((const float4*)(Wq + (size_t)z*16*CC))[t];
    ((float4*)Wl[1])[t] = ((const float4*)(Wk + (size_t)z*16*CC))[t];
    ((float4*)Wl[2])[t] = ((const float4*)(Wv + (size_t)z*16*CC))[t];
    for (int i = t; i < CC*64; i += 256) {
        int ic = i >> 6, p = i & 63;
        xs[ic][p] = x[((size_t)n*CC + ic)*HW + px0 + p];
    }
    __syncthreads();

    float aq[4], ak[4], av[4];
    #pragma unroll
    for (int j = 0; j < 4; ++j) { aq[j] = bq[oc0+j]; ak[j] = bk[oc0+j]; av[j] = bv[oc0+j]; }

    for (int ic = 0; ic < CC; ic += 4) {
        float xv0 = xs[ic  ][px];
        float xv1 = xs[ic+1][px];
        float xv2 = xs[ic+2][px];
        float xv3 = xs[ic+3][px];
        #pragma unroll
        for (int j = 0; j < 4; ++j) {
            const int row = (ocl+j)*CC + ic;
            float4 wq = *(const float4*)&Wl[0][row];
            float4 wk = *(const float4*)&Wl[1][row];
            float4 wv = *(const float4*)&Wl[2][row];
            aq[j] = fmaf(wq.x,xv0, fmaf(wq.y,xv1, fmaf(wq.z,xv2, fmaf(wq.w,xv3, aq[j]))));
            ak[j] = fmaf(wk.x,xv0, fmaf(wk.y,xv1, fmaf(wk.z,xv2, fmaf(wk.w,xv3, ak[j]))));
            av[j] = fmaf(wv.x,xv0, fmaf(wv.y,xv1, fmaf(wv.z,xv2, fmaf(wv.w,xv3, av[j]))));
        }
    }

    const size_t base = ((size_t)n*HW + px0 + px)*CC + oc0;
    half4 vq, vk;
    #pragma unroll
    for (int j = 0; j < 4; ++j) { vq[j] = (f16)aq[j]; vk[j] = (f16)ak[j]; }
    *(half4*)&q[base] = vq;
    *(half4*)&k[base] = vk;

    #pragma unroll
    for (int j = 0; j < 4; ++j) {
        size_t gi = ((size_t)n*CC + oc0 + j)*HW + px0 + px;
        gv[gi] = (f16)((h0[gi] + h1[gi]) * av[j]);
    }

    float* slot = ws + PART_OFF + (size_t)(n*(HW/64) + blockIdx.x)*256;
    #pragma unroll
    for (int j = 0; j < 4; ++j) {
        float v0 = aq[j], v1 = aq[j]*aq[j], v2 = ak[j], v3 = ak[j]*ak[j];
        #pragma unroll
        for (int off = 32; off > 0; off >>= 1) {
            v0 += __shfl_down(v0, off);
            v1 += __shfl_down(v1, off);
            v2 += __shfl_down(v2, off);
            v3 += __shfl_down(v3, off);
        }
        if (px == 0) {
            slot[      oc0 + j] = v0;
            slot[ 64 + oc0 + j] = v1;
            slot[128 + oc0 + j] = v2;
            slot[192 + oc0 + j] = v3;
        }
    }
}

// ---------------------------------------------------------------------------
__global__ __launch_bounds__(256)
void bnstats_kernel(const float* __restrict__ gq, const float* __restrict__ betaq,
                    const float* __restrict__ gk, const float* __restrict__ betak,
                    float* __restrict__ ws)
{
    __shared__ float tot[256];
    const int i = threadIdx.x;
    float acc = 0.0f;
    #pragma unroll 8
    for (int b = 0; b < 256; ++b) acc += ws[PART_OFF + b*256 + i];
    tot[i] = acc;
    __syncthreads();

    if (i < 64) {
        float mean = tot[i] * (1.0f / NT);
        float var  = tot[64 + i] * (1.0f / NT) - mean*mean;
        float s    = gq[i] * rsqrtf(var + EPSV);
        ws[256 + i] = s;
        ws[320 + i] = betaq[i] - mean*s;
    } else if (i < 128) {
        int c = i - 64;
        float mean = tot[128 + c] * (1.0f / NT);
        float var  = tot[192 + c] * (1.0f / NT) - mean*mean;
        float s    = gk[c] * rsqrtf(var + EPSV);
        ws[384 + c] = s * LOG2E;
        ws[448 + c] = (betak[c] - mean*s) * LOG2E;
    }
}

// ---------------------------------------------------------------------------
__global__ __launch_bounds__(256)
void apply_kernel(f16* __restrict__ q, f16* __restrict__ k,
                  const float* __restrict__ ws)
{
    __shared__ float sc[CC], sh[CC];
    const int t = threadIdx.x;
    const int tens = blockIdx.y;
    if (t < 64)       sc[t]    = ws[256 + tens*128 + t];
    else if (t < 128) sh[t-64] = ws[320 + tens*128 + (t-64)];
    __syncthreads();

    f16* p = tens ? k : q;
    const size_t e0 = ((size_t)blockIdx.x * 256 + t) * 8;
    const int c0 = (int)(e0 & 63);

    half8 v = *(half8*)&p[e0];
    half8 o;
    #pragma unroll
    for (int j = 0; j < 8; ++j)
        o[j] = (f16)fmaxf(fmaf(sc[c0+j], (float)v[j], sh[c0+j]), 0.0f);
    *(half8*)&p[e0] = o;
}

// ---------------------------------------------------------------------------
// MFMA flash attention, S^T form, EXACT online softmax with LAZY RESCALE:
// p = exp2(s - m_running) <= 1 always (no f16 overflow, exact). The O/l
// rescale block runs only when the running max actually increases —
// guarded by a wave-uniform __any (expected ~ln(16)≈3 of 16 steps); rows
// whose max didn't change get al = exp2(0) = 1 (bit-exact vs r9).
// l accumulates via ones-operand MFMA (full cross-quad row-sum in the
// matrix pipe; no end-of-loop shuffle reduce).
// grid (HW/64, NB) = 256 blocks, 512 thr; wave w owns keys [w*512,+512).
// Layout (validated r4-r9): mfma(X,Y) -> D[p=quad*4+reg <- X row][q=lane&15 <- Y row].
// ---------------------------------------------------------------------------
__global__ __launch_bounds__(512, 2)
void attn_kernel(const f16* __restrict__ q, const f16* __restrict__ k,
                 const f16* __restrict__ gv, float* __restrict__ out)
{
    __shared__ float Obuf[8][4][256];   // [wave][ct][lane*4] — 32 KB, reused 4x
    __shared__ float MLbuf[2][8][64];   // [m|l][wave][qrow]  — 4 KB

    const int t    = threadIdx.x;
    const int n    = blockIdx.y;
    const int w    = t >> 6;
    const int lane = t & 63;
    const int m16  = lane & 15;
    const int kb   = lane >> 4;
    const int q0   = blockIdx.x * 64;

    half8 qf[4][2];
    #pragma unroll
    for (int qt = 0; qt < 4; ++qt) {
        const size_t qb = ((size_t)n*HW + q0 + qt*16 + m16)*CC + kb*8;
        qf[qt][0] = *(const half8*)&q[qb];
        qf[qt][1] = *(const half8*)&q[qb + 32];
    }

    const int    kt0   = w * 512;
    const size_t krow  = (size_t)n*HW*CC;
    const size_t gbase = ((size_t)n*CC + m16)*HW;

    half8 khf[2][2][2];     // [buf][ktile][chalf]
    half4 gvf[2][2][4];     // [buf][ktile][ct]
    const half4 ones = {(f16)1.f, (f16)1.f, (f16)1.f, (f16)1.f};

#define LOADK(B, KT) do {                                                     \
    size_t a_ = krow + ((size_t)(KT) + m16)*CC + kb*8;                        \
    khf[B][0][0] = *(const half8*)&k[a_];                                     \
    khf[B][0][1] = *(const half8*)&k[a_ + 32];                                \
    khf[B][1][0] = *(const half8*)&k[a_ + 16*CC];                             \
    khf[B][1][1] = *(const half8*)&k[a_ + 16*CC + 32];                        \
} while (0)

#define LOADGV(B, KT) do {                                                    \
    size_t g_ = gbase + (size_t)(KT) + kb*4;                                  \
    _Pragma("unroll") for (int k2_ = 0; k2_ < 2; ++k2_)                       \
    _Pragma("unroll") for (int ct_ = 0; ct_ < 4; ++ct_)                       \
        gvf[B][k2_][ct_] = *(const half4*)&gv[g_ + k2_*16 + (size_t)ct_*16*HW];\
} while (0)

    float4v accO[4][4], accL[4];
    #pragma unroll
    for (int qt = 0; qt < 4; ++qt) {
        #pragma unroll
        for (int ct = 0; ct < 4; ++ct) accO[qt][ct] = (float4v){0.f,0.f,0.f,0.f};
        accL[qt] = (float4v){0.f,0.f,0.f,0.f};
    }
    float m[4] = {-INFINITY,-INFINITY,-INFINITY,-INFINITY};

#define STEP(B, NB_, KTN) do {                                                \
    LOADK(NB_, KTN);                                                          \
    LOADGV(NB_, KTN);                                                         \
    float4v accS[4][2];                                                       \
    _Pragma("unroll") for (int qt_ = 0; qt_ < 4; ++qt_)                       \
    _Pragma("unroll") for (int k2_ = 0; k2_ < 2; ++k2_) {                     \
        float4v z_ = {0.f,0.f,0.f,0.f};                                       \
        z_ = __builtin_amdgcn_mfma_f32_16x16x32_f16(khf[B][k2_][0], qf[qt_][0], z_, 0,0,0); \
        accS[qt_][k2_] = __builtin_amdgcn_mfma_f32_16x16x32_f16(khf[B][k2_][1], qf[qt_][1], z_, 0,0,0); \
    }                                                                         \
    float mx[4];                                                              \
    _Pragma("unroll") for (int qt_ = 0; qt_ < 4; ++qt_) {                     \
        float v_ = fmaxf(fmaxf(fmaxf(accS[qt_][0][0], accS[qt_][0][1]),       \
                               fmaxf(accS[qt_][0][2], accS[qt_][0][3])),      \
                         fmaxf(fmaxf(accS[qt_][1][0], accS[qt_][1][1]),       \
                               fmaxf(accS[qt_][1][2], accS[qt_][1][3])));     \
        v_ = fmaxf(v_, __shfl_xor(v_, 16));                                   \
        v_ = fmaxf(v_, __shfl_xor(v_, 32));                                   \
        mx[qt_] = v_;                                                         \
    }                                                                         \
    int need_ = (mx[0] > m[0]) | (mx[1] > m[1]) |                             \
                (mx[2] > m[2]) | (mx[3] > m[3]);                              \
    if (__any(need_)) {                                                       \
        _Pragma("unroll") for (int qt_ = 0; qt_ < 4; ++qt_) {                 \
            float mn_ = fmaxf(m[qt_], mx[qt_]);                               \
            float al_ = exp2f(m[qt_] - mn_);                                  \
            m[qt_] = mn_;                                                     \
            accL[qt_][0]*=al_; accL[qt_][1]*=al_;                             \
            accL[qt_][2]*=al_; accL[qt_][3]*=al_;                             \
            _Pragma("unroll") for (int ct_ = 0; ct_ < 4; ++ct_) {             \
                accO[qt_][ct_][0]*=al_; accO[qt_][ct_][1]*=al_;               \
                accO[qt_][ct_][2]*=al_; accO[qt_][ct_][3]*=al_;               \
            }                                                                 \
        }                                                                     \
    }                                                                         \
    _Pragma("unroll") for (int qt_ = 0; qt_ < 4; ++qt_) {                     \
        float p0 = exp2f(accS[qt_][0][0]-m[qt_]), p1 = exp2f(accS[qt_][0][1]-m[qt_]); \
        float p2 = exp2f(accS[qt_][0][2]-m[qt_]), p3 = exp2f(accS[qt_][0][3]-m[qt_]); \
        float p4 = exp2f(accS[qt_][1][0]-m[qt_]), p5 = exp2f(accS[qt_][1][1]-m[qt_]); \
        float p6 = exp2f(accS[qt_][1][2]-m[qt_]), p7 = exp2f(accS[qt_][1][3]-m[qt_]); \
        half4 pfa, pfb;                                                       \
        pfa[0]=(f16)p0; pfa[1]=(f16)p1; pfa[2]=(f16)p2; pfa[3]=(f16)p3;       \
        pfb[0]=(f16)p4; pfb[1]=(f16)p5; pfb[2]=(f16)p6; pfb[3]=(f16)p7;       \
        accL[qt_] = __builtin_amdgcn_mfma_f32_16x16x16f16(ones, pfa, accL[qt_], 0,0,0); \
        accL[qt_] = __builtin_amdgcn_mfma_f32_16x16x16f16(ones, pfb, accL[qt_], 0,0,0); \
        _Pragma("unroll") for (int ct_ = 0; ct_ < 4; ++ct_) {                 \
            float4v o_ = accO[qt_][ct_];                                      \
            o_ = __builtin_amdgcn_mfma_f32_16x16x16f16(gvf[B][0][ct_], pfa, o_, 0,0,0); \
            accO[qt_][ct_] = __builtin_amdgcn_mfma_f32_16x16x16f16(gvf[B][1][ct_], pfb, o_, 0,0,0); \
        }                                                                     \
    }                                                                         \
} while (0)

    LOADK(0, kt0);
    LOADGV(0, kt0);
    for (int i2 = 0; i2 < 8; ++i2) {
        const int kA = kt0 + i2*64;
        STEP(0, 1, kA + 32);
        STEP(1, 0, kA + 64);   // final prefetch overreads into ws slack: unused
    }

    // publish (m, l) per q-row — accL already holds the full cross-quad sum
    if (kb == 0) {
        #pragma unroll
        for (int qt = 0; qt < 4; ++qt) {
            MLbuf[0][w][qt*16 + m16] = m[qt];
            MLbuf[1][w][qt*16 + m16] = accL[qt][0];
        }
    }
    __syncthreads();

    // global M, L per q-row; scale own partials into the shared frame
    float invL[4];
    #pragma unroll
    for (int qt = 0; qt < 4; ++qt) {
        const int r = qt*16 + m16;
        float M = MLbuf[0][0][r];
        #pragma unroll
        for (int src = 1; src < 8; ++src) M = fmaxf(M, MLbuf[0][src][r]);
        float L = 0.0f;
        #pragma unroll
        for (int src = 0; src < 8; ++src)
            L += MLbuf[1][src][r] * exp2f(MLbuf[0][src][r] - M);
        const float f = exp2f(m[qt] - M);
        #pragma unroll
        for (int ct = 0; ct < 4; ++ct) {
            accO[qt][ct][0] *= f; accO[qt][ct][1] *= f;
            accO[qt][ct][2] *= f; accO[qt][ct][3] *= f;
        }
        invL[qt] = 1.0f / L;
    }

    // 4 staged merge rounds: round rd handles q-tile rd
    for (int rd = 0; rd < 4; ++rd) {
        __syncthreads();
        #pragma unroll
        for (int ct = 0; ct < 4; ++ct)
            ((float4*)&Obuf[w][ct][0])[lane] =
                (float4){accO[rd][ct][0], accO[rd][ct][1], accO[rd][ct][2], accO[rd][ct][3]};
        __syncthreads();
        if (w < 4) {
            float4 s = ((float4*)&Obuf[0][w][0])[lane];
            #pragma unroll
            for (int src = 1; src < 8; ++src) {
                float4 v = ((float4*)&Obuf[src][w][0])[lane];
                s.x += v.x; s.y += v.y; s.z += v.z; s.w += v.w;
            }
            const float iv = invL[rd];
            const int chb = w*16 + kb*4;
            const int row = q0 + rd*16 + m16;
            out[((size_t)n*CC + chb + 0)*HW + row] = s.x * iv;
            out[((size_t)n*CC + chb + 1)*HW + row] = s.y * iv;
            out[((size_t)n*CC + chb + 2)*HW + row] = s.z * iv;
            out[((size_t)n*CC + chb + 3)*HW + row] = s.w * iv;
        }
    }
#undef STEP
#undef LOADGV
#undef LOADK
}

// ---------------------------------------------------------------------------
extern "C" void kernel_launch(void* const* d_in, const int* in_sizes, int n_in,
                              void* d_out, int out_size, void* d_ws, size_t ws_size,
                              hipStream_t stream)
{
    const float* low   = (const float*)d_in[0];
    const float* h0    = (const float*)d_in[1];
    const float* h1    = (const float*)d_in[2];
    const float* Wq    = (const float*)d_in[3];
    const float* bq    = (const float*)d_in[4];
    const float* gq    = (const float*)d_in[5];
    const float* betaq = (const float*)d_in[6];
    const float* Wk    = (const float*)d_in[7];
    const float* bk    = (const float*)d_in[8];
    const float* gk    = (const float*)d_in[9];
    const float* betak = (const float*)d_in[10];
    const float* Wv    = (const float*)d_in[11];
    const float* bv    = (const float*)d_in[12];

    float* wsf = (float*)d_ws;
    float* out = (float*)d_out;

    f16* q  = (f16*)((char*)d_ws + TEN_OFF);
    f16* k  = q + NELEM;
    f16* gv = k + NELEM;

    conv2_kernel<<<dim3(HW/64, NB, 4), 256, 0, stream>>>(
        low, h0, h1, Wq, bq, Wk, bk, Wv, bv, wsf, q, k, gv);

    bnstats_kernel<<<1, 256, 0, stream>>>(gq, betaq, gk, betak, wsf);

    apply_kernel<<<dim3((int)(NELEM/(256*8)), 2), 256, 0, stream>>>(q, k, wsf);

    attn_kernel<<<dim3(HW/64, NB), 512, 0, stream>>>(q, k, gv, out);
}